// Round 3
// baseline (192.378 us; speedup 1.0000x reference)
//
#include <hip/hip_runtime.h>
#include <hip/hip_fp16.h>
#include <hip/hip_cooperative_groups.h>
#include <cstdint>

// Problem constants
#define B_TOT  65536
#define D_TOT  256
#define H_SUB  16

// Per-feature piecewise-linear LUT over x in [-8, 8], 256 cells
#define TBL_N      256
#define TBL_XMIN   (-8.0f)
#define TBL_DELTA  0.0625f
#define INV_DELTA  16.0f
#define T_OFF      128.0f     // -TBL_XMIN * INV_DELTA

// Tiling
#define DG      32                 // features per group
#define NG      (D_TOT / DG)       // 8 groups
#define RPB     512                // rows per block
#define NTH     256
#define NBLK    ((B_TOT / RPB) * NG)   // 1024 = exactly 4 blocks/CU co-resident

__device__ __forceinline__ float tanh_fast(float z) {
    float e = __builtin_amdgcn_exp2f(z * 2.8853900817779268f);
    return 1.0f - 2.0f * __builtin_amdgcn_rcpf(e + 1.0f);
}

// ---------------------------------------------------------------------------
// Single cooperative kernel.
// Phase 1 (blocks 0..255): block = feature d. Thread i computes
//   f_d(x_i) = sum_h w2[d,h]*tanh(w1[d,h]*x_i + b1[d,h])  (16 tanh/thread,
// shared through LDS so value+slope need only 257 evaluations per feature),
// writes LUT entry half2(f_i + b2[d], f_{i+1} - f_i) to ws, and zeros its
// slice of d_out (256 blocks x 256 threads == B_TOT). Blocks 256+ idle.
// grid.sync() makes ws/out visible device-wide.
// Phase 2 (all 1024 blocks): identical to R2 kan_forward — coalesced
// streaming gather, 32 KiB LDS LUT, shfl row-reduce, 1 atomicAdd/row/group.
// ---------------------------------------------------------------------------
__global__ __launch_bounds__(NTH, 4) void kan_fused(
        const float* __restrict__ x,
        const float* __restrict__ w1,
        const float* __restrict__ b1,
        const float* __restrict__ w2,
        const float* __restrict__ b2,
        uint32_t* __restrict__ tab,
        float* __restrict__ out) {
    __shared__ uint32_t sT[DG * TBL_N];            // 32 KiB (phase 2)
    // phase 1 scratch aliases the same LDS (phase 2 refills after grid sync)
    float* sF = reinterpret_cast<float*>(sT);      // 257 floats used

    // ---------------- Phase 1: build LUTs + zero out ----------------
    if (blockIdx.x < D_TOT) {
        const int d = blockIdx.x;
        const int i = threadIdx.x;
        out[d * NTH + i] = 0.0f;

        float a[H_SUB], c[H_SUB], w[H_SUB];
#pragma unroll
        for (int h = 0; h < H_SUB; ++h) {
            a[h] = w1[d * H_SUB + h];
            c[h] = b1[d * H_SUB + h];
            w[h] = w2[d * H_SUB + h];
        }
        float x0 = TBL_XMIN + (float)i * TBL_DELTA;
        float f0 = 0.0f;
#pragma unroll
        for (int h = 0; h < H_SUB; ++h)
            f0 += w[h] * tanh_fast(fmaf(a[h], x0, c[h]));
        sF[i] = f0;
        if (i == NTH - 1) {                        // extra endpoint f(x_256)
            float xe = TBL_XMIN + (float)TBL_N * TBL_DELTA;
            float fe = 0.0f;
#pragma unroll
            for (int h = 0; h < H_SUB; ++h)
                fe += w[h] * tanh_fast(fmaf(a[h], xe, c[h]));
            sF[TBL_N] = fe;
        }
        __syncthreads();
        float val = sF[i] + b2[d];
        float slp = sF[i + 1] - sF[i];
        __half2 h2 = __halves2half2(__float2half_rn(val), __float2half_rn(slp));
        tab[d * TBL_N + i] = *reinterpret_cast<uint32_t*>(&h2);
        __threadfence();                           // device-scope visibility
    }

    cooperative_groups::this_grid().sync();

    // ---------------- Phase 2: streaming gather ----------------
    const int g  = blockIdx.x & (NG - 1);
    const int bc = blockIdx.x >> 3;                // NG == 8

    __syncthreads();                               // sF reuse done everywhere
    {
        const uint4* src = reinterpret_cast<const uint4*>(tab + g * DG * TBL_N);
        uint4* dst = reinterpret_cast<uint4*>(sT);
#pragma unroll
        for (int k = 0; k < (DG * TBL_N / 4) / NTH; ++k)
            dst[threadIdx.x + k * NTH] = src[threadIdx.x + k * NTH];
    }
    __syncthreads();

    const int lane   = threadIdx.x & 63;
    const int wave   = threadIdx.x >> 6;
    const int subrow = lane >> 3;                  // 0..7
    const int fq     = lane & 7;                   // feature quad 0..7

    const int row0 = bc * RPB + wave * 8 + subrow;
    const float* xb = x + (size_t)row0 * D_TOT + g * DG + fq * 4;

#pragma unroll 4
    for (int it = 0; it < RPB / 32; ++it) {        // 16 iters, 32 rows/block/iter
        const float4 xv =
            *reinterpret_cast<const float4*>(xb + (size_t)it * 32 * D_TOT);
        float xs[4] = {xv.x, xv.y, xv.z, xv.w};
        float acc = 0.0f;
#pragma unroll
        for (int c2 = 0; c2 < 4; ++c2) {
            float t = fmaf(xs[c2], INV_DELTA, T_OFF);
            t = fminf(fmaxf(t, 0.0f), 255.99f);
            float fi = floorf(t);
            float u = t - fi;
            uint32_t e = sT[(fq * 4 + c2) * TBL_N + (int)fi];
            union { uint32_t u32; __half2 h2; } cv;
            cv.u32 = e;
            acc += fmaf(__high2float(cv.h2), u, __low2float(cv.h2));
        }
        acc += __shfl_xor(acc, 1);
        acc += __shfl_xor(acc, 2);
        acc += __shfl_xor(acc, 4);
        if (fq == 0)
            atomicAdd(&out[row0 + it * 32], acc);
    }
}

extern "C" void kernel_launch(void* const* d_in, const int* in_sizes, int n_in,
                              void* d_out, int out_size, void* d_ws, size_t ws_size,
                              hipStream_t stream) {
    const float* x  = (const float*)d_in[0];
    const float* w1 = (const float*)d_in[1];
    const float* b1 = (const float*)d_in[2];
    const float* w2 = (const float*)d_in[3];
    const float* b2 = (const float*)d_in[4];
    float* out = (float*)d_out;
    uint32_t* tab = (uint32_t*)d_ws;               // 256 KiB

    void* args[] = {(void*)&x, (void*)&w1, (void*)&b1, (void*)&w2,
                    (void*)&b2, (void*)&tab, (void*)&out};
    hipLaunchCooperativeKernel(reinterpret_cast<void*>(kan_fused),
                               dim3(NBLK), dim3(NTH), args, 0, stream);
}

// Round 4
// 107.032 us; speedup vs baseline: 1.7974x; 1.7974x over previous
//
#include <hip/hip_runtime.h>
#include <hip/hip_fp16.h>
#include <cstdint>

// Problem constants
#define B_TOT  65536
#define D_TOT  256
#define H_SUB  16

// Per-feature piecewise-linear LUT over x in [-8, 8], 256 cells
#define TBL_N      256
#define TBL_XMIN   (-8.0f)
#define TBL_DELTA  0.0625f
#define INV_DELTA  16.0f
#define T_OFF      128.0f     // -TBL_XMIN * INV_DELTA

// Main-kernel tiling
#define DG      32                 // features per group
#define NG      (D_TOT / DG)       // 8 groups
#define RPB     512                // rows per block
#define NTH     256

__device__ __forceinline__ float tanh_fast(float z) {
    float e = __builtin_amdgcn_exp2f(z * 2.8853900817779268f);
    return 1.0f - 2.0f * __builtin_amdgcn_rcpf(e + 1.0f);
}

// ---------------------------------------------------------------------------
// Kernel 1: build LUTs + zero d_out. One block per feature d; thread i
// computes f_d(x_i) once (16 tanh), shares through LDS so value+slope need
// 257 evaluations per feature instead of 512. Grid totals B_TOT threads, so
// out-zeroing folds in (d_out is poisoned 0xAA before every timed launch).
// ---------------------------------------------------------------------------
__global__ __launch_bounds__(NTH) void build_tables(
        const float* __restrict__ w1,
        const float* __restrict__ b1,
        const float* __restrict__ w2,
        const float* __restrict__ b2,
        uint32_t* __restrict__ tab,
        float* __restrict__ out) {
    __shared__ float sF[TBL_N + 1];
    const int d = blockIdx.x;                      // 0..255
    const int i = threadIdx.x;                     // 0..255 (== LUT cell)
    out[d * NTH + i] = 0.0f;                       // 256*256 == B_TOT

    float a[H_SUB], c[H_SUB], w[H_SUB];
#pragma unroll
    for (int h = 0; h < H_SUB; ++h) {
        a[h] = w1[d * H_SUB + h];
        c[h] = b1[d * H_SUB + h];
        w[h] = w2[d * H_SUB + h];
    }
    float x0 = TBL_XMIN + (float)i * TBL_DELTA;
    float f0 = 0.0f;
#pragma unroll
    for (int h = 0; h < H_SUB; ++h)
        f0 += w[h] * tanh_fast(fmaf(a[h], x0, c[h]));
    sF[i] = f0;
    if (i == NTH - 1) {                            // endpoint f(x_256)
        float xe = TBL_XMIN + (float)TBL_N * TBL_DELTA;
        float fe = 0.0f;
#pragma unroll
        for (int h = 0; h < H_SUB; ++h)
            fe += w[h] * tanh_fast(fmaf(a[h], xe, c[h]));
        sF[TBL_N] = fe;
    }
    __syncthreads();
    float val = sF[i] + b2[d];
    float slp = sF[i + 1] - sF[i];
    __half2 h2 = __halves2half2(__float2half_rn(val), __float2half_rn(slp));
    tab[d * TBL_N + i] = *reinterpret_cast<uint32_t*>(&h2);
}

// ---------------------------------------------------------------------------
// Kernel 2: coalesced streaming gather (R2 structure — measured ~5-7 us).
// Block = (group g of 32 features, chunk of 512 rows). 32 KiB LDS table ->
// 4 blocks/CU. Lane ell = (subrow = ell>>3, featquad = ell&7): one
// global_load_dwordx4 covers 8 rows x 128B contiguous segments. unroll 8
// keeps 8 loads in flight against L3-hit latency. Row sum via 3 shfl_xor;
// lane fq==0 does one atomicAdd per row per group.
// ---------------------------------------------------------------------------
__global__ __launch_bounds__(NTH, 4) void kan_forward(
        const float* __restrict__ x,
        const uint32_t* __restrict__ tab,
        float* __restrict__ out) {
    __shared__ uint32_t sT[DG * TBL_N];            // 32 KiB

    const int g  = blockIdx.x & (NG - 1);
    const int bc = blockIdx.x >> 3;                // NG == 8

    {
        const uint4* src = reinterpret_cast<const uint4*>(tab + g * DG * TBL_N);
        uint4* dst = reinterpret_cast<uint4*>(sT);
#pragma unroll
        for (int k = 0; k < (DG * TBL_N / 4) / NTH; ++k)
            dst[threadIdx.x + k * NTH] = src[threadIdx.x + k * NTH];
    }
    __syncthreads();

    const int lane   = threadIdx.x & 63;
    const int wave   = threadIdx.x >> 6;
    const int subrow = lane >> 3;                  // 0..7
    const int fq     = lane & 7;                   // feature quad 0..7

    const int row0 = bc * RPB + wave * 8 + subrow;
    const float* xb = x + (size_t)row0 * D_TOT + g * DG + fq * 4;

#pragma unroll 8
    for (int it = 0; it < RPB / 32; ++it) {        // 16 iters, 32 rows/block/iter
        const float4 xv =
            *reinterpret_cast<const float4*>(xb + (size_t)it * 32 * D_TOT);
        float xs[4] = {xv.x, xv.y, xv.z, xv.w};
        float acc = 0.0f;
#pragma unroll
        for (int c = 0; c < 4; ++c) {
            float t = fmaf(xs[c], INV_DELTA, T_OFF);
            t = fminf(fmaxf(t, 0.0f), 255.99f);
            float fi = floorf(t);
            float u = t - fi;
            uint32_t e = sT[(fq * 4 + c) * TBL_N + (int)fi];
            union { uint32_t u32; __half2 h2; } cv;
            cv.u32 = e;
            acc += fmaf(__high2float(cv.h2), u, __low2float(cv.h2));
        }
        acc += __shfl_xor(acc, 1);
        acc += __shfl_xor(acc, 2);
        acc += __shfl_xor(acc, 4);
        if (fq == 0)
            atomicAdd(&out[row0 + it * 32], acc);
    }
}

extern "C" void kernel_launch(void* const* d_in, const int* in_sizes, int n_in,
                              void* d_out, int out_size, void* d_ws, size_t ws_size,
                              hipStream_t stream) {
    const float* x  = (const float*)d_in[0];
    const float* w1 = (const float*)d_in[1];
    const float* b1 = (const float*)d_in[2];
    const float* w2 = (const float*)d_in[3];
    const float* b2 = (const float*)d_in[4];
    float* out = (float*)d_out;
    uint32_t* tab = (uint32_t*)d_ws;               // 256 KiB of d_ws

    build_tables<<<dim3(D_TOT), dim3(NTH), 0, stream>>>(
        w1, b1, w2, b2, tab, out);

    kan_forward<<<dim3((B_TOT / RPB) * NG), dim3(NTH), 0, stream>>>(
        x, tab, out);
}